// Round 2
// baseline (289.884 us; speedup 1.0000x reference)
//
#include <hip/hip_runtime.h>
#include <hip/hip_bf16.h>
#include <math.h>

// Problem constants (B,L,H,D fixed by setup_inputs; S == L)
#define B_   4
#define L_   2048
#define H_   8
#define D_   64
#define NTOP 38          // int(5*ln(2048)) = 38
#define SAMPK 38
#define NIDX (L_*SAMPK)  // 77824

// Verified RNG (r10 PASS): JAX partitionable threefry WITH randint key-split:
//   k2 = threefry((0,42), (0,1));  idx[t] = (y0^y1 @ (k2,(0,t))) & 2047.

// ---- d_ws layout ----
#define CHUNK 256
#define NCH   (L_ / CHUNK)              // 8
#define NSLOT (B_ * H_ * NTOP * NCH)    // 9728

#define WS_M_OFF    0                       // float  M[65536]     = 262144 B
#define WS_MTOP_OFF 262144                  // int    mtop[32*38]  =   4864 B
#define WS_SMALL    (WS_MTOP_OFF + 4864)    // 267008 B
#define WS_PMAX_OFF WS_SMALL                // float[9728] = 38912 B
#define WS_PSUM_OFF (WS_PMAX_OFF + 38912)   // float[9728] = 38912 B
#define WS_PPV_OFF  (WS_PSUM_OFF + 38912)   // float[9728*64] = 2490368 B
#define WS_BIG      (WS_PPV_OFF + 2490368)  // 2835200 B

// ---------------- Threefry-2x32 (standard 20-round, KAT-verified) ----------------
__device__ __forceinline__ uint32_t rotl32(uint32_t v, int d) {
  return (v << d) | (v >> (32 - d));
}

__device__ __forceinline__ void threefry2x32(uint32_t k0, uint32_t k1,
                                             uint32_t x0, uint32_t x1,
                                             uint32_t& y0, uint32_t& y1) {
  const uint32_t ks2 = k0 ^ k1 ^ 0x1BD11BDAu;
  const uint32_t ks[3] = {k0, k1, ks2};
  x0 += k0; x1 += k1;
  const int ra[4] = {13, 15, 26, 6};
  const int rb[4] = {17, 29, 16, 24};
#pragma unroll
  for (int g = 0; g < 5; ++g) {
    const int* r = (g & 1) ? rb : ra;
#pragma unroll
    for (int i = 0; i < 4; ++i) {
      x0 += x1;
      x1 = rotl32(x1, r[i]);
      x1 ^= x0;
    }
    x0 += ks[(g + 1) % 3];
    x1 += ks[(g + 2) % 3] + (uint32_t)(g + 1);
  }
  y0 = x0; y1 = x1;
}

__device__ __forceinline__ int sample_idx(int t) {
  uint32_t k2_0, k2_1, y0, y1;
  threefry2x32(0u, 42u, 0u, 1u, k2_0, k2_1);          // k2 = split(key(42))[1]
  threefry2x32(k2_0, k2_1, 0u, (uint32_t)t, y0, y1);  // partitionable draw
  return (int)((y0 ^ y1) & 2047u);
}

// ---------------- k1': fused m + cumsum (cumsum blocks first, stream in m's shadow) ----
// bI < 64           : cumsum path (bh x dhalf), 8 chunks of 256 rows, 2 barriers.
// bI in [64, 4160)  : m path, identical to the verified m_kernel with bI' = bI-64.
__global__ __launch_bounds__(256) void m_cumsum_kernel(const float* __restrict__ Q,
                                                       const float* __restrict__ K,
                                                       const float* __restrict__ V,
                                                       float* __restrict__ M,
                                                       float* __restrict__ out) {
  __shared__ uint16_t sidx[16][SAMPK];   // m path
  __shared__ float cs[8][32];            // cumsum path

  int tid = threadIdx.x;

  if (blockIdx.x < 64) {
    // ---- cumsum: out[b,:,h,d] = inclusive cumsum of V along L ----
    int bI = blockIdx.x;
    int bh = bI >> 1, dhalf = bI & 1;
    int h = bh & (H_ - 1), b = bh >> 3;
    int dl = tid & 31, c = tid >> 5;       // 8 chunks of 256 rows
    const int CH = L_ / 8;                 // 256
    int d = dhalf * 32 + dl;
    size_t base = ((size_t)b * L_ * H_ + h) * D_ + d;
    const size_t ls = (size_t)H_ * D_;     // 512
    float s = 0.f;
    for (int l = c * CH; l < (c + 1) * CH; ++l)
      s += V[base + (size_t)l * ls];
    cs[c][dl] = s;
    __syncthreads();
    float run = 0.f;
    for (int cc = 0; cc < c; ++cc) run += cs[cc][dl];
    for (int l = c * CH; l < (c + 1) * CH; ++l) {
      run += V[base + (size_t)l * ls];
      out[base + (size_t)l * ls] = run;
    }
    return;
  }

  // ---- m path (verified r13 structure) ----
  int bI = blockIdx.x - 64;             // 0..4095
  int j8 = bI >> 3;                     // 0..511
  int bh = (bI & 7) + 8 * (j8 >> 7);    // blockIdx%8 == bh%8 -> same XCD
  int chunk = j8 & 127;                 // 128 chunks of 16 q per bh
  int grp = tid >> 4, c = tid & 15;     // 16 groups x 16 lanes
  int q = chunk * 16 + grp;
  int h = bh & (H_ - 1), b = bh >> 3;

  for (int s = tid; s < 16 * SAMPK; s += 256) {
    int ql = s / SAMPK, jj = s - ql * SAMPK;
    sidx[ql][jj] = (uint16_t)sample_idx((chunk * 16 + ql) * SAMPK + jj);
  }
  __syncthreads();

  float4 qv = *(const float4*)(Q + (((size_t)b * L_ + q) * H_ + h) * D_ + 4 * c);
  const float* Kbase = K + ((size_t)b * L_ * H_ + h) * D_ + 4 * c;

  float mx = -1e30f, smv = 0.f;
  for (int j = 0; j < SAMPK; ++j) {
    int row = (int)sidx[grp][j];
    float4 kv = *(const float4*)(Kbase + (size_t)row * (H_ * D_));
    float part = qv.x * kv.x + qv.y * kv.y + qv.z * kv.z + qv.w * kv.w;
#pragma unroll
    for (int off = 1; off < 16; off <<= 1)
      part += __shfl_xor(part, off);
    mx = fmaxf(mx, part);
    smv += part;
  }
  if (c == 0)
    M[(size_t)bh * L_ + q] = mx - smv * (1.0f / (float)L_);
}

// ---------------- k2': top-38 per (b,h), ONE WAVE per block, zero barriers in loop ----
// Per-lane strided candidates cached in regs; argmax via 6-step shuffle butterfly
// (tie -> lower index, matching lax.top_k stability). Only the winner's owner lane
// touches LDS again (own-lane dependency only), so no cross-lane sync is needed.
__global__ __launch_bounds__(64) void topk1w_kernel(const float* __restrict__ M,
                                                    int* __restrict__ mtop) {
  int bh = blockIdx.x;
  int lane = threadIdx.x;
  __shared__ float sm[L_];
  const float* Mrow = M + (size_t)bh * L_;
  for (int i = lane; i < L_; i += 64) sm[i] = Mrow[i];
  __syncthreads();

  float bv = -1e38f; int bi = -1;
  for (int i = lane; i < L_; i += 64) {
    float v = sm[i];
    if (v > bv) { bv = v; bi = i; }     // ascending -> lowest idx on tie
  }

  for (int u = 0; u < NTOP; ++u) {
    float v = bv; int i = bi;
#pragma unroll
    for (int off = 1; off < 64; off <<= 1) {
      float v2 = __shfl_xor(v, off);
      int   i2 = __shfl_xor(i, off);
      if (v2 > v || (v2 == v && i2 >= 0 && (i < 0 || i2 < i))) { v = v2; i = i2; }
    }
    int sel = (i < 0) ? 0 : i;          // all lanes agree (butterfly is full)
    if (lane == 0) mtop[bh * NTOP + u] = sel;
    if (bi == sel) {                    // only the owner lane (sel%64) can match
      sm[sel] = -1e38f;
      bv = -1e38f; bi = -1;
      for (int i2 = lane; i2 < L_; i2 += 64) {
        float vv = sm[i2];
        if (vv > bv) { bv = vv; bi = i2; }
      }
    }
  }
}

// ---------------- k4a': split-K attention partials, 2 barriers per block ----------------
// Scores live in registers (group-replicated); max/sum/PV reduced by wave shuffles
// (sum/PV only over offsets 16/32 because values are replicated across the 16 lanes
// of a group), with one tiny LDS stage to combine the 4 waves.
__global__ __launch_bounds__(256) void attn_part_kernel(const float* __restrict__ Q,
                                                        const float* __restrict__ K,
                                                        const float* __restrict__ V,
                                                        const int* __restrict__ mtop,
                                                        float* __restrict__ pmax,
                                                        float* __restrict__ psum,
                                                        float* __restrict__ ppv) {
  int bI = blockIdx.x;
  int c = bI & 7;                 // chunk (== XCD)
  int uu = bI >> 3;               // 0..1215 == bh*NTOP + u
  int bh = uu / NTOP;
  int h = bh & (H_ - 1), b = bh >> 3;

  int pos = mtop[uu];
  if (pos < 0) pos = 0;
  if (pos > L_ - 1) pos = L_ - 1;
  int klen = pos + 1;
  int kstart = c * CHUNK;
  if (kstart >= klen) return;     // uniform early exit (no barriers crossed)
  int kcnt = min(CHUNK, klen - kstart);

  int tid = threadIdx.x;
  int c16 = tid & 15, g = tid >> 4;   // 16 groups x 16 lanes
  int wid = tid >> 6;

  __shared__ float wmax[4];
  __shared__ float wsum[4];
  __shared__ float4 part4[4][16];

  float4 qreg = *(const float4*)(Q + (((size_t)b * L_ + pos) * H_ + h) * D_ + 4 * c16);
  const float* Kbase = K + ((size_t)b * L_ * H_ + h) * D_ + 4 * c16;
  const float* Vbase = V + ((size_t)b * L_ * H_ + h) * D_ + 4 * c16;

  // QK^T: group g owns rows k = g + 16*i; scores kept in regs (lane-replicated)
  float s[16];
  float lmax = -1e30f;
#pragma unroll
  for (int i = 0; i < 16; ++i) {
    s[i] = -1e30f;
    int k = g + 16 * i;
    if (k < kcnt) {
      float4 kv = *(const float4*)(Kbase + (size_t)(kstart + k) * (H_ * D_));
      float part = qreg.x * kv.x + qreg.y * kv.y + qreg.z * kv.z + qreg.w * kv.w;
#pragma unroll
      for (int off = 1; off < 16; off <<= 1)
        part += __shfl_xor(part, off);
      s[i] = part * 0.125f;           // 1/sqrt(64)
      lmax = fmaxf(lmax, s[i]);
    }
  }

  // block max: full wave butterfly (max is replication-safe) + 4-wave LDS combine
#pragma unroll
  for (int off = 1; off < 64; off <<= 1)
    lmax = fmaxf(lmax, __shfl_xor(lmax, off));
  if ((tid & 63) == 0) wmax[wid] = lmax;
  __syncthreads();                    // barrier 1
  float mx = fmaxf(fmaxf(wmax[0], wmax[1]), fmaxf(wmax[2], wmax[3]));

  // exp + sum (per-thread on own rows; replicated across the 16 lanes of a group)
  float p[16];
  float lsum = 0.f;
#pragma unroll
  for (int i = 0; i < 16; ++i) {
    int k = g + 16 * i;
    if (k < kcnt) {
      p[i] = expf(s[i] - mx);
      lsum += p[i];
    } else {
      p[i] = 0.f;
    }
  }
  // sum across the 4 groups of this wave ONLY (offsets 16,32; 1..8 would x16-count)
  lsum += __shfl_xor(lsum, 16);
  lsum += __shfl_xor(lsum, 32);
  if ((tid & 63) == 0) wsum[wid] = lsum;

  // PV partial (unnormalized, relative to block max mx)
  float4 acc = make_float4(0.f, 0.f, 0.f, 0.f);
#pragma unroll
  for (int i = 0; i < 16; ++i) {
    int k = g + 16 * i;
    if (k < kcnt) {
      float4 v4 = *(const float4*)(Vbase + (size_t)(kstart + k) * (H_ * D_));
      acc.x += p[i] * v4.x; acc.y += p[i] * v4.y;
      acc.z += p[i] * v4.z; acc.w += p[i] * v4.w;
    }
  }
  // reduce across the 4 groups of this wave (offsets 16,32)
  acc.x += __shfl_xor(acc.x, 16); acc.y += __shfl_xor(acc.y, 16);
  acc.z += __shfl_xor(acc.z, 16); acc.w += __shfl_xor(acc.w, 16);
  acc.x += __shfl_xor(acc.x, 32); acc.y += __shfl_xor(acc.y, 32);
  acc.z += __shfl_xor(acc.z, 32); acc.w += __shfl_xor(acc.w, 32);
  if ((tid & 63) < 16) part4[wid][c16] = acc;
  __syncthreads();                    // barrier 2 (covers wsum + part4)

  int slot = uu * NCH + c;
  if (tid < 16) {
    float4 r = part4[0][tid];
    float4 a1 = part4[1][tid], a2 = part4[2][tid], a3 = part4[3][tid];
    r.x += a1.x + a2.x + a3.x; r.y += a1.y + a2.y + a3.y;
    r.z += a1.z + a2.z + a3.z; r.w += a1.w + a2.w + a3.w;
    *(float4*)(ppv + (size_t)slot * D_ + 4 * tid) = r;
  }
  if (tid == 0) {
    pmax[slot] = mx;
    psum[slot] = wsum[0] + wsum[1] + wsum[2] + wsum[3];
  }
}

// ---------------- k4b: combine chunk partials, write out row ----------------
__global__ __launch_bounds__(64) void attn_fin_kernel(const float* __restrict__ pmax,
                                                      const float* __restrict__ psum,
                                                      const float* __restrict__ ppv,
                                                      const int* __restrict__ mtop,
                                                      float* __restrict__ out) {
  int uu = blockIdx.x;            // 0..1215 == bh*NTOP + u
  int bh = uu / NTOP;
  int h = bh & (H_ - 1), b = bh >> 3;
  int pos = mtop[uu];
  if (pos < 0) pos = 0;
  if (pos > L_ - 1) pos = L_ - 1;
  int klen = pos + 1;
  int nch = (klen + CHUNK - 1) / CHUNK;
  int tid = threadIdx.x;          // == d

  int base = uu * NCH;
  float gmax = -1e30f;
#pragma unroll
  for (int cc = 0; cc < NCH; ++cc)
    if (cc < nch) gmax = fmaxf(gmax, pmax[base + cc]);

  float w0, gsum = 0.f, acc = 0.f;
#pragma unroll
  for (int cc = 0; cc < NCH; ++cc) {
    if (cc < nch) {
      w0 = expf(pmax[base + cc] - gmax);
      gsum += psum[base + cc] * w0;
      acc += ppv[(size_t)(base + cc) * D_ + tid] * w0;
    }
  }
  out[(((size_t)b * L_ + pos) * H_ + h) * D_ + tid] = acc / gsum;
}

// ================= fallback kernels (small-ws / zero-ws paths, unchanged) =================
__global__ __launch_bounds__(256) void m_kernel(const float* __restrict__ Q,
                                                const float* __restrict__ K,
                                                float* __restrict__ M) {
  int bI = blockIdx.x;
  int j8 = bI >> 3;
  int bh = (bI & 7) + 8 * (j8 >> 7);
  int chunk = j8 & 127;
  int tid = threadIdx.x;
  int grp = tid >> 4, c = tid & 15;
  int q = chunk * 16 + grp;
  int h = bh & (H_ - 1), b = bh >> 3;

  __shared__ uint16_t sidx[16][SAMPK];
  for (int s = tid; s < 16 * SAMPK; s += 256) {
    int ql = s / SAMPK, jj = s - ql * SAMPK;
    sidx[ql][jj] = (uint16_t)sample_idx((chunk * 16 + ql) * SAMPK + jj);
  }
  __syncthreads();

  float4 qv = *(const float4*)(Q + (((size_t)b * L_ + q) * H_ + h) * D_ + 4 * c);
  const float* Kbase = K + ((size_t)b * L_ * H_ + h) * D_ + 4 * c;

  float mx = -1e30f, smv = 0.f;
  for (int j = 0; j < SAMPK; ++j) {
    int row = (int)sidx[grp][j];
    float4 kv = *(const float4*)(Kbase + (size_t)row * (H_ * D_));
    float part = qv.x * kv.x + qv.y * kv.y + qv.z * kv.z + qv.w * kv.w;
#pragma unroll
    for (int off = 1; off < 16; off <<= 1)
      part += __shfl_xor(part, off);
    mx = fmaxf(mx, part);
    smv += part;
  }
  if (c == 0)
    M[(size_t)bh * L_ + q] = mx - smv * (1.0f / (float)L_);
}

__global__ __launch_bounds__(1024) void cumsum_kernel(const float* __restrict__ V,
                                                      float* __restrict__ out) {
  int bI = blockIdx.x;
  int bh = bI >> 1, dhalf = bI & 1;
  int h = bh & (H_ - 1), b = bh >> 3;
  int tid = threadIdx.x;
  int dl = tid & 31, c = tid >> 5;
  int d = dhalf * 32 + dl;
  const int CH = L_ / 32;
  __shared__ float cs[32][32];
  size_t base = ((size_t)b * L_ * H_ + h) * D_ + d;
  const size_t ls = (size_t)H_ * D_;
  float s = 0.f;
  for (int l = c * CH; l < (c + 1) * CH; ++l)
    s += V[base + (size_t)l * ls];
  cs[c][dl] = s;
  __syncthreads();
  float run = 0.f;
  for (int cc = 0; cc < c; ++cc) run += cs[cc][dl];
  for (int l = c * CH; l < (c + 1) * CH; ++l) {
    run += V[base + (size_t)l * ls];
    out[base + (size_t)l * ls] = run;
  }
}

__global__ __launch_bounds__(256) void attn_kernel(const float* __restrict__ Q,
                                                   const float* __restrict__ K,
                                                   const float* __restrict__ V,
                                                   const int* __restrict__ mtop,
                                                   float* __restrict__ out) {
  int bI = blockIdx.x;
  int j = bI >> 3;
  int u = j % NTOP;
  int bh = (bI & 7) + 8 * (j / NTOP);
  int h = bh & (H_ - 1), b = bh >> 3;
  int tid = threadIdx.x;

  int pos = mtop[bh * NTOP + u];
  if (pos < 0) pos = 0;
  if (pos > L_ - 1) pos = L_ - 1;
  int klen = pos + 1;

  __shared__ float qs[D_];
  __shared__ float sc[L_];
  __shared__ float redv[256];
  __shared__ float4 part4[16][16];

  if (tid < D_)
    qs[tid] = Q[(((size_t)b * L_ + pos) * H_ + h) * D_ + tid];
  __syncthreads();

  int c16 = tid & 15, g = tid >> 4;
  float4 qreg = *(const float4*)(qs + 4 * c16);
  const float* Kbase = K + ((size_t)b * L_ * H_ + h) * D_ + 4 * c16;
  float lmax = -1e30f;
  for (int k = g; k < klen; k += 16) {
    float4 kv = *(const float4*)(Kbase + (size_t)k * (H_ * D_));
    float part = qreg.x * kv.x + qreg.y * kv.y + qreg.z * kv.z + qreg.w * kv.w;
#pragma unroll
    for (int off = 1; off < 16; off <<= 1)
      part += __shfl_xor(part, off);
    part *= 0.125f;
    if (c16 == 0) sc[k] = part;
    lmax = fmaxf(lmax, part);
  }
  redv[tid] = lmax;
  __syncthreads();
  for (int s = 128; s > 0; s >>= 1) {
    if (tid < s) redv[tid] = fmaxf(redv[tid], redv[tid + s]);
    __syncthreads();
  }
  float mx = redv[0];
  __syncthreads();

  float lsum = 0.f;
  for (int k = tid; k < klen; k += 256) {
    float p = expf(sc[k] - mx);
    sc[k] = p;
    lsum += p;
  }
  redv[tid] = lsum;
  __syncthreads();
  for (int s = 128; s > 0; s >>= 1) {
    if (tid < s) redv[tid] += redv[tid + s];
    __syncthreads();
  }
  float inv = 1.0f / redv[0];
  __syncthreads();

  float4 acc = make_float4(0.f, 0.f, 0.f, 0.f);
  const float* Vbase = V + ((size_t)b * L_ * H_ + h) * D_ + 4 * c16;
  for (int k = g; k < klen; k += 16) {
    float p = sc[k];
    float4 v4 = *(const float4*)(Vbase + (size_t)k * (H_ * D_));
    acc.x += p * v4.x; acc.y += p * v4.y; acc.z += p * v4.z; acc.w += p * v4.w;
  }
  part4[g][c16] = acc;
  __syncthreads();
#pragma unroll
  for (int s = 8; s > 0; s >>= 1) {
    if (g < s) {
      float4 o = part4[g + s][c16];
      float4 m = part4[g][c16];
      m.x += o.x; m.y += o.y; m.z += o.z; m.w += o.w;
      part4[g][c16] = m;
    }
    __syncthreads();
  }
  if (tid < 16) {
    float4 r = part4[0][tid];
    r.x *= inv; r.y *= inv; r.z *= inv; r.w *= inv;
    *(float4*)(out + (((size_t)b * L_ + pos) * H_ + h) * D_ + 4 * tid) = r;
  }
}

__global__ __launch_bounds__(256) void topk_kernel(const float* __restrict__ M,
                                                   int* __restrict__ mtop) {
  int bh = blockIdx.x;
  int tid = threadIdx.x;
  __shared__ float sm[L_];
  __shared__ float wv[4];
  __shared__ int   wi[4];
  __shared__ int   ssel;
  const float* Mrow = M + (size_t)bh * L_;
  for (int i = tid; i < L_; i += 256) sm[i] = Mrow[i];
  __syncthreads();

  float bv = -1e38f; int bi = -1;
  for (int i = tid; i < L_; i += 256) {
    float v = sm[i];
    if (v > bv) { bv = v; bi = i; }
  }

  int lane = tid & 63, wid = tid >> 6;
  for (int u = 0; u < NTOP; ++u) {
    float v = bv; int i = bi;
#pragma unroll
    for (int off = 32; off > 0; off >>= 1) {
      float v2 = __shfl_down(v, off);
      int   i2 = __shfl_down(i, off);
      if (v2 > v || (v2 == v && i2 >= 0 && (i < 0 || i2 < i))) { v = v2; i = i2; }
    }
    if (lane == 0) { wv[wid] = v; wi[wid] = i; }
    __syncthreads();
    if (tid == 0) {
      float fv = wv[0]; int fi = wi[0];
#pragma unroll
      for (int w = 1; w < 4; ++w) {
        if (wv[w] > fv || (wv[w] == fv && wi[w] >= 0 && (fi < 0 || wi[w] < fi))) {
          fv = wv[w]; fi = wi[w];
        }
      }
      if (fi < 0) fi = 0;
      mtop[bh * NTOP + u] = fi;
      sm[fi] = -1e38f;
      ssel = fi;
    }
    __syncthreads();
    int sel = ssel;
    if (bi == sel) {
      bv = -1e38f; bi = -1;
      for (int i2 = tid; i2 < L_; i2 += 256) {
        float vv = sm[i2];
        if (vv > bv) { bv = vv; bi = i2; }
      }
    }
  }
}

__global__ __launch_bounds__(256) void fused_kernel(const float* __restrict__ Q,
                                                    const float* __restrict__ K,
                                                    const float* __restrict__ V,
                                                    float* __restrict__ out) {
  int bh = blockIdx.x;
  int h = bh % H_, b = bh / H_;
  int tid = threadIdx.x;

  __shared__ float sm[L_];
  __shared__ float redv[256];
  __shared__ int   redi[256];
  __shared__ int   mtop_s[NTOP];
  __shared__ float qs[D_];
  __shared__ float part[4][D_];

  for (int q = tid; q < L_; q += 256) {
    const float4* q4 = (const float4*)(Q + (((size_t)b * L_ + q) * H_ + h) * D_);
    float4 qv[16];
#pragma unroll
    for (int i = 0; i < 16; ++i) qv[i] = q4[i];
    float mx = -1e30f, smv = 0.f;
    for (int j = 0; j < SAMPK; ++j) {
      int kk = sample_idx(q * SAMPK + j);
      const float4* k4 = (const float4*)(K + (((size_t)b * L_ + kk) * H_ + h) * D_);
      float dot = 0.f;
#pragma unroll
      for (int i = 0; i < 16; ++i) {
        float4 kv = k4[i];
        dot += qv[i].x * kv.x + qv[i].y * kv.y + qv[i].z * kv.z + qv[i].w * kv.w;
      }
      mx = fmaxf(mx, dot);
      smv += dot;
    }
    sm[q] = mx - smv * (1.0f / (float)L_);
  }
  __syncthreads();

  for (int u = 0; u < NTOP; ++u) {
    float bv = -1e38f; int bi = -1;
    for (int i = tid; i < L_; i += 256) {
      float v = sm[i];
      if (v > bv) { bv = v; bi = i; }
    }
    redv[tid] = bv; redi[tid] = bi;
    __syncthreads();
    for (int s = 128; s > 0; s >>= 1) {
      if (tid < s) {
        float v2 = redv[tid + s]; int i2 = redi[tid + s];
        if (v2 > redv[tid] ||
            (v2 == redv[tid] && i2 >= 0 && (redi[tid] < 0 || i2 < redi[tid]))) {
          redv[tid] = v2; redi[tid] = i2;
        }
      }
      __syncthreads();
    }
    if (tid == 0) {
      int sel = redi[0];
      if (sel < 0) sel = 0;
      mtop_s[u] = sel;
      sm[sel] = -1e38f;
    }
    __syncthreads();
  }

  for (int u = 0; u < NTOP; ++u) {
    int pos = mtop_s[u];
    if (pos < 0) pos = 0;
    if (pos > L_ - 1) pos = L_ - 1;
    int klen = pos + 1;

    __syncthreads();
    if (tid < D_)
      qs[tid] = Q[(((size_t)b * L_ + pos) * H_ + h) * D_ + tid];
    __syncthreads();

    float lmax = -1e30f;
    for (int k = tid; k < klen; k += 256) {
      const float4* k4 = (const float4*)(K + (((size_t)b * L_ + k) * H_ + h) * D_);
      float dot = 0.f;
#pragma unroll
      for (int i = 0; i < 16; ++i) {
        float4 kv = k4[i];
        dot += qs[4 * i] * kv.x + qs[4 * i + 1] * kv.y
             + qs[4 * i + 2] * kv.z + qs[4 * i + 3] * kv.w;
      }
      dot *= 0.125f;
      sm[k] = dot;
      lmax = fmaxf(lmax, dot);
    }
    redv[tid] = lmax;
    __syncthreads();
    for (int s = 128; s > 0; s >>= 1) {
      if (tid < s) redv[tid] = fmaxf(redv[tid], redv[tid + s]);
      __syncthreads();
    }
    float mx = redv[0];
    __syncthreads();

    float lsum = 0.f;
    for (int k = tid; k < klen; k += 256) {
      float p = expf(sm[k] - mx);
      sm[k] = p;
      lsum += p;
    }
    redv[tid] = lsum;
    __syncthreads();
    for (int s = 128; s > 0; s >>= 1) {
      if (tid < s) redv[tid] += redv[tid + s];
      __syncthreads();
    }
    float inv = 1.0f / redv[0];
    __syncthreads();

    int d = tid & 63, slice = tid >> 6;
    float acc = 0.f;
    for (int k = slice; k < klen; k += 4)
      acc += sm[k] * V[(((size_t)b * L_ + k) * H_ + h) * D_ + d];
    part[slice][d] = acc;
    __syncthreads();
    if (tid < D_) {
      float r = (part[0][tid] + part[1][tid]) + (part[2][tid] + part[3][tid]);
      out[(((size_t)b * L_ + pos) * H_ + h) * D_ + tid] = r * inv;
    }
  }
}

extern "C" void kernel_launch(void* const* d_in, const int* in_sizes, int n_in,
                              void* d_out, int out_size, void* d_ws, size_t ws_size,
                              hipStream_t stream) {
  const float* Q = (const float*)d_in[0];
  const float* K = (const float*)d_in[1];
  const float* V = (const float*)d_in[2];
  float* out = (float*)d_out;

  if (ws_size >= (size_t)WS_BIG) {
    char* ws = (char*)d_ws;
    float* M    = (float*)(ws + WS_M_OFF);
    int*   mt   = (int*)(ws + WS_MTOP_OFF);
    float* pmax = (float*)(ws + WS_PMAX_OFF);
    float* psum = (float*)(ws + WS_PSUM_OFF);
    float* ppv  = (float*)(ws + WS_PPV_OFF);

    m_cumsum_kernel<<<4160, 256, 0, stream>>>(Q, K, V, M, out);
    topk1w_kernel<<<B_ * H_, 64, 0, stream>>>(M, mt);
    attn_part_kernel<<<NSLOT, 256, 0, stream>>>(Q, K, V, mt, pmax, psum, ppv);
    attn_fin_kernel<<<B_ * H_ * NTOP, 64, 0, stream>>>(pmax, psum, ppv, mt, out);
  } else if (ws_size >= (size_t)WS_SMALL) {
    char* ws = (char*)d_ws;
    float* M  = (float*)(ws + WS_M_OFF);
    int*   mt = (int*)(ws + WS_MTOP_OFF);

    m_kernel<<<4096, 256, 0, stream>>>(Q, K, M);
    topk_kernel<<<B_ * H_, 256, 0, stream>>>(M, mt);
    cumsum_kernel<<<B_ * H_ * 2, 1024, 0, stream>>>(V, out);
    attn_kernel<<<B_ * H_ * NTOP, 256, 0, stream>>>(Q, K, V, mt, out);
  } else {
    cumsum_kernel<<<B_ * H_ * 2, 1024, 0, stream>>>(V, out);
    fused_kernel<<<B_ * H_, 256, 0, stream>>>(Q, K, V, out);
  }
}

// Round 3
// 267.622 us; speedup vs baseline: 1.0832x; 1.0832x over previous
//
#include <hip/hip_runtime.h>
#include <hip/hip_bf16.h>
#include <math.h>

// Problem constants (B,L,H,D fixed by setup_inputs; S == L)
#define B_   4
#define L_   2048
#define H_   8
#define D_   64
#define NTOP 38          // int(5*ln(2048)) = 38
#define SAMPK 38

// Verified RNG (r10 PASS): JAX partitionable threefry WITH randint key-split:
//   k2 = threefry((0,42), (0,1));  idx[t] = (y0^y1 @ (k2,(0,t))) & 2047.

// ---- d_ws layouts ----
// 16-chunk path (CHUNK=128, K+V in LDS):
#define WS_M_OFF    0                        // float  M[65536]     = 262144 B
#define WS_MTOP_OFF 262144                   // int    mtop[32*38]  =   4864 B
#define WS_SMALL    (WS_MTOP_OFF + 4864)     // 267008 B
// 8-chunk layout (r1-compatible, 2.84 MB known to fit):
#define NSLOT8      (B_ * H_ * NTOP * 8)     // 9728
#define WS8_PMAX    WS_SMALL
#define WS8_PSUM    (WS8_PMAX + NSLOT8 * 4)
#define WS8_PPV     (WS8_PSUM + NSLOT8 * 4)
#define WS8_TOTAL   (WS8_PPV + NSLOT8 * D_ * 4)          // 2835200
// 16-chunk layout (5.4 MB):
#define NSLOT16     (B_ * H_ * NTOP * 16)    // 19456
#define WS16_PMAX   WS_SMALL
#define WS16_PSUM   (WS16_PMAX + NSLOT16 * 4)
#define WS16_PPV    (WS16_PSUM + NSLOT16 * 4)
#define WS16_TOTAL  (WS16_PPV + NSLOT16 * D_ * 4)        // 5403392

// ---------------- Threefry-2x32 (standard 20-round, KAT-verified) ----------------
__device__ __forceinline__ uint32_t rotl32(uint32_t v, int d) {
  return (v << d) | (v >> (32 - d));
}

__device__ __forceinline__ void threefry2x32(uint32_t k0, uint32_t k1,
                                             uint32_t x0, uint32_t x1,
                                             uint32_t& y0, uint32_t& y1) {
  const uint32_t ks2 = k0 ^ k1 ^ 0x1BD11BDAu;
  const uint32_t ks[3] = {k0, k1, ks2};
  x0 += k0; x1 += k1;
  const int ra[4] = {13, 15, 26, 6};
  const int rb[4] = {17, 29, 16, 24};
#pragma unroll
  for (int g = 0; g < 5; ++g) {
    const int* r = (g & 1) ? rb : ra;
#pragma unroll
    for (int i = 0; i < 4; ++i) {
      x0 += x1;
      x1 = rotl32(x1, r[i]);
      x1 ^= x0;
    }
    x0 += ks[(g + 1) % 3];
    x1 += ks[(g + 2) % 3] + (uint32_t)(g + 1);
  }
  y0 = x0; y1 = x1;
}

__device__ __forceinline__ int sample_idx(int t) {
  uint32_t k2_0, k2_1, y0, y1;
  threefry2x32(0u, 42u, 0u, 1u, k2_0, k2_1);          // k2 = split(key(42))[1]
  threefry2x32(k2_0, k2_1, 0u, (uint32_t)t, y0, y1);  // partitionable draw
  return (int)((y0 ^ y1) & 2047u);
}

// ---------------- k1: fused m + cumsum (cumsum blocks stream in m's shadow) ----
// bI < 64           : cumsum path (bh x dhalf), 8 chunks of 256 rows, 1 barrier.
// bI in [64, 4160)  : m path; j-loop 2-way unrolled (bitwise-identical M:
//                     same dot/butterfly order, same mx/smv sequence).
__global__ __launch_bounds__(256) void m_cumsum_kernel(const float* __restrict__ Q,
                                                       const float* __restrict__ K,
                                                       const float* __restrict__ V,
                                                       float* __restrict__ M,
                                                       float* __restrict__ out) {
  __shared__ uint16_t sidx[16][SAMPK];   // m path
  __shared__ float cs[8][32];            // cumsum path

  int tid = threadIdx.x;

  if (blockIdx.x < 64) {
    int bI = blockIdx.x;
    int bh = bI >> 1, dhalf = bI & 1;
    int h = bh & (H_ - 1), b = bh >> 3;
    int dl = tid & 31, c = tid >> 5;       // 8 chunks of 256 rows
    const int CH = L_ / 8;                 // 256
    int d = dhalf * 32 + dl;
    size_t base = ((size_t)b * L_ * H_ + h) * D_ + d;
    const size_t ls = (size_t)H_ * D_;     // 512
    float s = 0.f;
    for (int l = c * CH; l < (c + 1) * CH; ++l)
      s += V[base + (size_t)l * ls];
    cs[c][dl] = s;
    __syncthreads();
    float run = 0.f;
    for (int cc = 0; cc < c; ++cc) run += cs[cc][dl];
    for (int l = c * CH; l < (c + 1) * CH; ++l) {
      run += V[base + (size_t)l * ls];
      out[base + (size_t)l * ls] = run;
    }
    return;
  }

  // ---- m path ----
  int bI = blockIdx.x - 64;             // 0..4095
  int j8 = bI >> 3;                     // 0..511
  int bh = (bI & 7) + 8 * (j8 >> 7);    // blockIdx%8 == bh%8 -> same XCD
  int chunk = j8 & 127;                 // 128 chunks of 16 q per bh
  int grp = tid >> 4, c = tid & 15;     // 16 groups x 16 lanes
  int q = chunk * 16 + grp;
  int h = bh & (H_ - 1), b = bh >> 3;

  for (int s = tid; s < 16 * SAMPK; s += 256) {
    int ql = s / SAMPK, jj = s - ql * SAMPK;
    sidx[ql][jj] = (uint16_t)sample_idx((chunk * 16 + ql) * SAMPK + jj);
  }
  __syncthreads();

  float4 qv = *(const float4*)(Q + (((size_t)b * L_ + q) * H_ + h) * D_ + 4 * c);
  const float* Kbase = K + ((size_t)b * L_ * H_ + h) * D_ + 4 * c;

  float mx = -1e30f, smv = 0.f;
  for (int j = 0; j < SAMPK; j += 2) {   // SAMPK even; 2-way MLP
    int r0 = (int)sidx[grp][j];
    int r1 = (int)sidx[grp][j + 1];
    float4 k0 = *(const float4*)(Kbase + (size_t)r0 * (H_ * D_));
    float4 k1 = *(const float4*)(Kbase + (size_t)r1 * (H_ * D_));
    float p0 = qv.x * k0.x + qv.y * k0.y + qv.z * k0.z + qv.w * k0.w;
    float p1 = qv.x * k1.x + qv.y * k1.y + qv.z * k1.z + qv.w * k1.w;
#pragma unroll
    for (int off = 1; off < 16; off <<= 1) {
      p0 += __shfl_xor(p0, off);
      p1 += __shfl_xor(p1, off);
    }
    mx = fmaxf(mx, p0); smv += p0;
    mx = fmaxf(mx, p1); smv += p1;
  }
  if (c == 0)
    M[(size_t)bh * L_ + q] = mx - smv * (1.0f / (float)L_);
}

// ---------------- k2: top-38, ONE WAVE, candidates fully in REGISTERS ----------------
// r2 lesson: 1-wave LDS rescan = 120cyc/ds_read serial -> 90us. Registers instead:
// 32 vals/lane; per-extraction = 32 unrolled reg compares + 6-shfl butterfly +
// unrolled mark. Zero LDS, zero barriers, no memory in the loop.
__global__ __launch_bounds__(64) void topk_reg_kernel(const float* __restrict__ M,
                                                      int* __restrict__ mtop) {
  int bh = blockIdx.x;
  int lane = threadIdx.x;
  const float* Mrow = M + (size_t)bh * L_;

  float vals[32];
#pragma unroll
  for (int i = 0; i < 32; ++i)
    vals[i] = Mrow[lane + 64 * i];     // coalesced 256B/instr

  for (int u = 0; u < NTOP; ++u) {
    // per-lane argmax over 32 regs (ascending idx, strict > -> lowest idx on tie)
    float bv = vals[0]; int bslot = 0;
#pragma unroll
    for (int i = 1; i < 32; ++i)
      if (vals[i] > bv) { bv = vals[i]; bslot = i; }
    float v = bv;
    int idx = lane + 64 * bslot;
    // 64-lane butterfly argmax, tie -> lowest global index (lax.top_k order)
#pragma unroll
    for (int off = 1; off < 64; off <<= 1) {
      float v2 = __shfl_xor(v, off);
      int   i2 = __shfl_xor(idx, off);
      if (v2 > v || (v2 == v && i2 < idx)) { v = v2; idx = i2; }
    }
    if (lane == 0) mtop[bh * NTOP + u] = idx;
    // mark extracted element (owner lane only; static reg indexing via unroll)
    if ((idx & 63) == lane) {
      int slot = idx >> 6;
#pragma unroll
      for (int i = 0; i < 32; ++i)
        if (i == slot) vals[i] = -1e38f;
    }
  }
}

// ---------------- k4a: chunk-resident attention partials ----------------
// r2 lesson: 9728 tiny blocks re-reading K/V from L2 38x = latency-bound.
// Invert: block = (bh, chunk). Stage chunk K (and V if VLDS) into LDS ONCE
// (rotation swizzle (c16+k)&15 -> concurrent groups hit disjoint banks), then
// each WAVE independently handles u = w, w+4, ... : 4 groups x CHUNKT/4 rows,
// pure shuffle reductions (offs 16/32 cross-group), zero barriers after staging.
template <int CHUNKT, int NCHT, bool VLDS>
__global__ __launch_bounds__(256) void attn_chunk_kernel(const float* __restrict__ Q,
                                                         const float* __restrict__ K,
                                                         const float* __restrict__ V,
                                                         const int* __restrict__ mtop,
                                                         float* __restrict__ pmax,
                                                         float* __restrict__ psum,
                                                         float* __restrict__ ppv) {
  __shared__ float4 sb[4096];          // 64 KB: K[CHUNKT][16] (+ V[CHUNKT][16] if VLDS)

  int bI = blockIdx.x;
  int c = bI & (NCHT - 1);
  int bh = bI / NCHT;
  int h = bh & (H_ - 1), b = bh >> 3;
  int kstart = c * CHUNKT;
  int tid = threadIdx.x;

  // block-uniform early exit (before any barrier)
  int maxpos = -1;
  for (int u = 0; u < NTOP; ++u) maxpos = max(maxpos, mtop[bh * NTOP + u]);
  if (maxpos < kstart) return;

  const float* Kb = K + ((size_t)b * L_ * H_ + h) * D_;
  const float* Vb = V + ((size_t)b * L_ * H_ + h) * D_;

  // stage: 16 block-groups x 16 lanes; wave reads 4 consecutive rows = 1KB/instr
  {
    int g16 = tid >> 4, c16s = tid & 15;
#pragma unroll
    for (int r = 0; r < CHUNKT / 16; ++r) {
      int row = g16 + 16 * r;
      float4 kv = *(const float4*)(Kb + (size_t)(kstart + row) * (H_ * D_) + 4 * c16s);
      sb[row * 16 + ((c16s + row) & 15)] = kv;
      if (VLDS) {
        float4 vv = *(const float4*)(Vb + (size_t)(kstart + row) * (H_ * D_) + 4 * c16s);
        sb[CHUNKT * 16 + row * 16 + ((c16s + row) & 15)] = vv;
      }
    }
  }
  __syncthreads();

  int lane = tid & 63, w = tid >> 6;
  int g = lane >> 4, c16 = lane & 15;       // 4 groups x 16 lanes per wave

  for (int u = w; u < NTOP; u += 4) {
    int pos = mtop[bh * NTOP + u];          // wave-uniform scalar load
    if (pos < kstart) continue;
    int kcnt = min(CHUNKT, pos + 1 - kstart);

    float4 qreg = *(const float4*)(Q + (((size_t)b * L_ + pos) * H_ + h) * D_ + 4 * c16);

    // scores: group g owns rows k = g + 4*i (group-uniform predicate -> shfl safe)
    float s[CHUNKT / 4];
    float lmax = -1e30f;
#pragma unroll
    for (int i = 0; i < CHUNKT / 4; ++i) {
      int k = g + 4 * i;
      s[i] = -1e30f;
      if (k < kcnt) {
        float4 kv = sb[k * 16 + ((c16 + k) & 15)];
        float part = qreg.x * kv.x + qreg.y * kv.y + qreg.z * kv.z + qreg.w * kv.w;
        part += __shfl_xor(part, 1);
        part += __shfl_xor(part, 2);
        part += __shfl_xor(part, 4);
        part += __shfl_xor(part, 8);
        s[i] = part * 0.125f;               // 1/sqrt(64)
        lmax = fmaxf(lmax, s[i]);
      }
    }
    // chunk max across the 4 groups (replication-safe)
    lmax = fmaxf(lmax, __shfl_xor(lmax, 16));
    lmax = fmaxf(lmax, __shfl_xor(lmax, 32));

    // exp + sum + PV partial
    float lsum = 0.f;
    float4 acc = make_float4(0.f, 0.f, 0.f, 0.f);
#pragma unroll
    for (int i = 0; i < CHUNKT / 4; ++i) {
      int k = g + 4 * i;
      if (k < kcnt) {
        float p = expf(s[i] - lmax);
        lsum += p;
        float4 v4;
        if (VLDS) v4 = sb[CHUNKT * 16 + k * 16 + ((c16 + k) & 15)];
        else      v4 = *(const float4*)(Vb + (size_t)(kstart + k) * (H_ * D_) + 4 * c16);
        acc.x += p * v4.x; acc.y += p * v4.y;
        acc.z += p * v4.z; acc.w += p * v4.w;
      }
    }
    // cross-group reduce (offsets 16/32 only: values replicated within group)
    lsum += __shfl_xor(lsum, 16);
    lsum += __shfl_xor(lsum, 32);
    acc.x += __shfl_xor(acc.x, 16); acc.y += __shfl_xor(acc.y, 16);
    acc.z += __shfl_xor(acc.z, 16); acc.w += __shfl_xor(acc.w, 16);
    acc.x += __shfl_xor(acc.x, 32); acc.y += __shfl_xor(acc.y, 32);
    acc.z += __shfl_xor(acc.z, 32); acc.w += __shfl_xor(acc.w, 32);

    int slot = (bh * NTOP + u) * NCHT + c;
    if (lane < 16)
      *(float4*)(ppv + (size_t)slot * D_ + 4 * c16) = acc;
    if (lane == 0) { pmax[slot] = lmax; psum[slot] = lsum; }
  }
}

// ---------------- k4b: combine chunk partials, write out row ----------------
template <int NCHT>
__global__ __launch_bounds__(64) void attn_fin_kernel(const float* __restrict__ pmax,
                                                      const float* __restrict__ psum,
                                                      const float* __restrict__ ppv,
                                                      const int* __restrict__ mtop,
                                                      float* __restrict__ out) {
  const int CH = L_ / NCHT;
  int uu = blockIdx.x;            // 0..1215 == bh*NTOP + u
  int bh = uu / NTOP;
  int h = bh & (H_ - 1), b = bh >> 3;
  int pos = mtop[uu];
  if (pos < 0) pos = 0;
  if (pos > L_ - 1) pos = L_ - 1;
  int klen = pos + 1;
  int nch = (klen + CH - 1) / CH;
  int tid = threadIdx.x;          // == d

  int base = uu * NCHT;
  float gmax = -1e30f;
#pragma unroll
  for (int cc = 0; cc < NCHT; ++cc)
    if (cc < nch) gmax = fmaxf(gmax, pmax[base + cc]);

  float gsum = 0.f, acc = 0.f;
#pragma unroll
  for (int cc = 0; cc < NCHT; ++cc) {
    if (cc < nch) {
      float w0 = expf(pmax[base + cc] - gmax);
      gsum += psum[base + cc] * w0;
      acc += ppv[(size_t)(base + cc) * D_ + tid] * w0;
    }
  }
  out[(((size_t)b * L_ + pos) * H_ + h) * D_ + tid] = acc / gsum;
}

// ================= fallback kernels (small-ws / zero-ws paths) =================
__global__ __launch_bounds__(256) void m_kernel(const float* __restrict__ Q,
                                                const float* __restrict__ K,
                                                float* __restrict__ M) {
  int bI = blockIdx.x;
  int j8 = bI >> 3;
  int bh = (bI & 7) + 8 * (j8 >> 7);
  int chunk = j8 & 127;
  int tid = threadIdx.x;
  int grp = tid >> 4, c = tid & 15;
  int q = chunk * 16 + grp;
  int h = bh & (H_ - 1), b = bh >> 3;

  __shared__ uint16_t sidx[16][SAMPK];
  for (int s = tid; s < 16 * SAMPK; s += 256) {
    int ql = s / SAMPK, jj = s - ql * SAMPK;
    sidx[ql][jj] = (uint16_t)sample_idx((chunk * 16 + ql) * SAMPK + jj);
  }
  __syncthreads();

  float4 qv = *(const float4*)(Q + (((size_t)b * L_ + q) * H_ + h) * D_ + 4 * c);
  const float* Kbase = K + ((size_t)b * L_ * H_ + h) * D_ + 4 * c;

  float mx = -1e30f, smv = 0.f;
  for (int j = 0; j < SAMPK; ++j) {
    int row = (int)sidx[grp][j];
    float4 kv = *(const float4*)(Kbase + (size_t)row * (H_ * D_));
    float part = qv.x * kv.x + qv.y * kv.y + qv.z * kv.z + qv.w * kv.w;
#pragma unroll
    for (int off = 1; off < 16; off <<= 1)
      part += __shfl_xor(part, off);
    mx = fmaxf(mx, part);
    smv += part;
  }
  if (c == 0)
    M[(size_t)bh * L_ + q] = mx - smv * (1.0f / (float)L_);
}

__global__ __launch_bounds__(1024) void cumsum_kernel(const float* __restrict__ V,
                                                      float* __restrict__ out) {
  int bI = blockIdx.x;
  int bh = bI >> 1, dhalf = bI & 1;
  int h = bh & (H_ - 1), b = bh >> 3;
  int tid = threadIdx.x;
  int dl = tid & 31, c = tid >> 5;
  int d = dhalf * 32 + dl;
  const int CH = L_ / 32;
  __shared__ float cs[32][32];
  size_t base = ((size_t)b * L_ * H_ + h) * D_ + d;
  const size_t ls = (size_t)H_ * D_;
  float s = 0.f;
  for (int l = c * CH; l < (c + 1) * CH; ++l)
    s += V[base + (size_t)l * ls];
  cs[c][dl] = s;
  __syncthreads();
  float run = 0.f;
  for (int cc = 0; cc < c; ++cc) run += cs[cc][dl];
  for (int l = c * CH; l < (c + 1) * CH; ++l) {
    run += V[base + (size_t)l * ls];
    out[base + (size_t)l * ls] = run;
  }
}

__global__ __launch_bounds__(256) void topk_kernel(const float* __restrict__ M,
                                                   int* __restrict__ mtop) {
  int bh = blockIdx.x;
  int tid = threadIdx.x;
  __shared__ float sm[L_];
  __shared__ float wv[4];
  __shared__ int   wi[4];
  __shared__ int   ssel;
  const float* Mrow = M + (size_t)bh * L_;
  for (int i = tid; i < L_; i += 256) sm[i] = Mrow[i];
  __syncthreads();

  float bv = -1e38f; int bi = -1;
  for (int i = tid; i < L_; i += 256) {
    float v = sm[i];
    if (v > bv) { bv = v; bi = i; }
  }

  int lane = tid & 63, wid = tid >> 6;
  for (int u = 0; u < NTOP; ++u) {
    float v = bv; int i = bi;
#pragma unroll
    for (int off = 32; off > 0; off >>= 1) {
      float v2 = __shfl_down(v, off);
      int   i2 = __shfl_down(i, off);
      if (v2 > v || (v2 == v && i2 >= 0 && (i < 0 || i2 < i))) { v = v2; i = i2; }
    }
    if (lane == 0) { wv[wid] = v; wi[wid] = i; }
    __syncthreads();
    if (tid == 0) {
      float fv = wv[0]; int fi = wi[0];
#pragma unroll
      for (int w = 1; w < 4; ++w) {
        if (wv[w] > fv || (wv[w] == fv && wi[w] >= 0 && (fi < 0 || wi[w] < fi))) {
          fv = wv[w]; fi = wi[w];
        }
      }
      if (fi < 0) fi = 0;
      mtop[bh * NTOP + u] = fi;
      sm[fi] = -1e38f;
      ssel = fi;
    }
    __syncthreads();
    int sel = ssel;
    if (bi == sel) {
      bv = -1e38f; bi = -1;
      for (int i2 = tid; i2 < L_; i2 += 256) {
        float vv = sm[i2];
        if (vv > bv) { bv = vv; bi = i2; }
      }
    }
  }
}

__global__ __launch_bounds__(256) void attn_kernel(const float* __restrict__ Q,
                                                   const float* __restrict__ K,
                                                   const float* __restrict__ V,
                                                   const int* __restrict__ mtop,
                                                   float* __restrict__ out) {
  int bI = blockIdx.x;
  int j = bI >> 3;
  int u = j % NTOP;
  int bh = (bI & 7) + 8 * (j / NTOP);
  int h = bh & (H_ - 1), b = bh >> 3;
  int tid = threadIdx.x;

  int pos = mtop[bh * NTOP + u];
  if (pos < 0) pos = 0;
  if (pos > L_ - 1) pos = L_ - 1;
  int klen = pos + 1;

  __shared__ float qs[D_];
  __shared__ float sc[L_];
  __shared__ float redv[256];
  __shared__ float4 part4[16][16];

  if (tid < D_)
    qs[tid] = Q[(((size_t)b * L_ + pos) * H_ + h) * D_ + tid];
  __syncthreads();

  int c16 = tid & 15, g = tid >> 4;
  float4 qreg = *(const float4*)(qs + 4 * c16);
  const float* Kbase = K + ((size_t)b * L_ * H_ + h) * D_ + 4 * c16;
  float lmax = -1e30f;
  for (int k = g; k < klen; k += 16) {
    float4 kv = *(const float4*)(Kbase + (size_t)k * (H_ * D_));
    float part = qreg.x * kv.x + qreg.y * kv.y + qreg.z * kv.z + qreg.w * kv.w;
#pragma unroll
    for (int off = 1; off < 16; off <<= 1)
      part += __shfl_xor(part, off);
    part *= 0.125f;
    if (c16 == 0) sc[k] = part;
    lmax = fmaxf(lmax, part);
  }
  redv[tid] = lmax;
  __syncthreads();
  for (int s = 128; s > 0; s >>= 1) {
    if (tid < s) redv[tid] = fmaxf(redv[tid], redv[tid + s]);
    __syncthreads();
  }
  float mx = redv[0];
  __syncthreads();

  float lsum = 0.f;
  for (int k = tid; k < klen; k += 256) {
    float p = expf(sc[k] - mx);
    sc[k] = p;
    lsum += p;
  }
  redv[tid] = lsum;
  __syncthreads();
  for (int s = 128; s > 0; s >>= 1) {
    if (tid < s) redv[tid] += redv[tid + s];
    __syncthreads();
  }
  float inv = 1.0f / redv[0];
  __syncthreads();

  float4 acc = make_float4(0.f, 0.f, 0.f, 0.f);
  const float* Vbase = V + ((size_t)b * L_ * H_ + h) * D_ + 4 * c16;
  for (int k = g; k < klen; k += 16) {
    float p = sc[k];
    float4 v4 = *(const float4*)(Vbase + (size_t)k * (H_ * D_));
    acc.x += p * v4.x; acc.y += p * v4.y; acc.z += p * v4.z; acc.w += p * v4.w;
  }
  part4[g][c16] = acc;
  __syncthreads();
#pragma unroll
  for (int s = 8; s > 0; s >>= 1) {
    if (g < s) {
      float4 o = part4[g + s][c16];
      float4 m = part4[g][c16];
      m.x += o.x; m.y += o.y; m.z += o.z; m.w += o.w;
      part4[g][c16] = m;
    }
    __syncthreads();
  }
  if (tid < 16) {
    float4 r = part4[0][tid];
    r.x *= inv; r.y *= inv; r.z *= inv; r.w *= inv;
    *(float4*)(out + (((size_t)b * L_ + pos) * H_ + h) * D_ + 4 * tid) = r;
  }
}

__global__ __launch_bounds__(256) void fused_kernel(const float* __restrict__ Q,
                                                    const float* __restrict__ K,
                                                    const float* __restrict__ V,
                                                    float* __restrict__ out) {
  int bh = blockIdx.x;
  int h = bh % H_, b = bh / H_;
  int tid = threadIdx.x;

  __shared__ float sm[L_];
  __shared__ float redv[256];
  __shared__ int   redi[256];
  __shared__ int   mtop_s[NTOP];
  __shared__ float qs[D_];
  __shared__ float part[4][D_];

  for (int q = tid; q < L_; q += 256) {
    const float4* q4 = (const float4*)(Q + (((size_t)b * L_ + q) * H_ + h) * D_);
    float4 qv[16];
#pragma unroll
    for (int i = 0; i < 16; ++i) qv[i] = q4[i];
    float mx = -1e30f, smv = 0.f;
    for (int j = 0; j < SAMPK; ++j) {
      int kk = sample_idx(q * SAMPK + j);
      const float4* k4 = (const float4*)(K + (((size_t)b * L_ + kk) * H_ + h) * D_);
      float dot = 0.f;
#pragma unroll
      for (int i = 0; i < 16; ++i) {
        float4 kv = k4[i];
        dot += qv[i].x * kv.x + qv[i].y * kv.y + qv[i].z * kv.z + qv[i].w * kv.w;
      }
      mx = fmaxf(mx, dot);
      smv += dot;
    }
    sm[q] = mx - smv * (1.0f / (float)L_);
  }
  __syncthreads();

  for (int u = 0; u < NTOP; ++u) {
    float bv = -1e38f; int bi = -1;
    for (int i = tid; i < L_; i += 256) {
      float v = sm[i];
      if (v > bv) { bv = v; bi = i; }
    }
    redv[tid] = bv; redi[tid] = bi;
    __syncthreads();
    for (int s = 128; s > 0; s >>= 1) {
      if (tid < s) {
        float v2 = redv[tid + s]; int i2 = redi[tid + s];
        if (v2 > redv[tid] ||
            (v2 == redv[tid] && i2 >= 0 && (redi[tid] < 0 || i2 < redi[tid]))) {
          redv[tid] = v2; redi[tid] = i2;
        }
      }
      __syncthreads();
    }
    if (tid == 0) {
      int sel = redi[0];
      if (sel < 0) sel = 0;
      mtop_s[u] = sel;
      sm[sel] = -1e38f;
    }
    __syncthreads();
  }

  for (int u = 0; u < NTOP; ++u) {
    int pos = mtop_s[u];
    if (pos < 0) pos = 0;
    if (pos > L_ - 1) pos = L_ - 1;
    int klen = pos + 1;

    __syncthreads();
    if (tid < D_)
      qs[tid] = Q[(((size_t)b * L_ + pos) * H_ + h) * D_ + tid];
    __syncthreads();

    float lmax = -1e30f;
    for (int k = tid; k < klen; k += 256) {
      const float4* k4 = (const float4*)(K + (((size_t)b * L_ + k) * H_ + h) * D_);
      float dot = 0.f;
#pragma unroll
      for (int i = 0; i < 16; ++i) {
        float4 kv = k4[i];
        dot += qs[4 * i] * kv.x + qs[4 * i + 1] * kv.y
             + qs[4 * i + 2] * kv.z + qs[4 * i + 3] * kv.w;
      }
      dot *= 0.125f;
      sm[k] = dot;
      lmax = fmaxf(lmax, dot);
    }
    redv[tid] = lmax;
    __syncthreads();
    for (int s = 128; s > 0; s >>= 1) {
      if (tid < s) redv[tid] = fmaxf(redv[tid], redv[tid + s]);
      __syncthreads();
    }
    float mx = redv[0];
    __syncthreads();

    float lsum = 0.f;
    for (int k = tid; k < klen; k += 256) {
      float p = expf(sm[k] - mx);
      sm[k] = p;
      lsum += p;
    }
    redv[tid] = lsum;
    __syncthreads();
    for (int s = 128; s > 0; s >>= 1) {
      if (tid < s) redv[tid] += redv[tid + s];
      __syncthreads();
    }
    float inv = 1.0f / redv[0];
    __syncthreads();

    int d = tid & 63, slice = tid >> 6;
    float acc = 0.f;
    for (int k = slice; k < klen; k += 4)
      acc += sm[k] * V[(((size_t)b * L_ + k) * H_ + h) * D_ + d];
    part[slice][d] = acc;
    __syncthreads();
    if (tid < D_) {
      float r = (part[0][tid] + part[1][tid]) + (part[2][tid] + part[3][tid]);
      out[(((size_t)b * L_ + pos) * H_ + h) * D_ + tid] = r * inv;
    }
  }
}

extern "C" void kernel_launch(void* const* d_in, const int* in_sizes, int n_in,
                              void* d_out, int out_size, void* d_ws, size_t ws_size,
                              hipStream_t stream) {
  const float* Q = (const float*)d_in[0];
  const float* K = (const float*)d_in[1];
  const float* V = (const float*)d_in[2];
  float* out = (float*)d_out;

  if (ws_size >= (size_t)WS16_TOTAL) {
    char* ws = (char*)d_ws;
    float* M    = (float*)(ws + WS_M_OFF);
    int*   mt   = (int*)(ws + WS_MTOP_OFF);
    float* pmax = (float*)(ws + WS16_PMAX);
    float* psum = (float*)(ws + WS16_PSUM);
    float* ppv  = (float*)(ws + WS16_PPV);

    m_cumsum_kernel<<<4160, 256, 0, stream>>>(Q, K, V, M, out);
    topk_reg_kernel<<<B_ * H_, 64, 0, stream>>>(M, mt);
    attn_chunk_kernel<128, 16, true><<<B_ * H_ * 16, 256, 0, stream>>>(
        Q, K, V, mt, pmax, psum, ppv);
    attn_fin_kernel<16><<<B_ * H_ * NTOP, 64, 0, stream>>>(pmax, psum, ppv, mt, out);
  } else if (ws_size >= (size_t)WS8_TOTAL) {
    char* ws = (char*)d_ws;
    float* M    = (float*)(ws + WS_M_OFF);
    int*   mt   = (int*)(ws + WS_MTOP_OFF);
    float* pmax = (float*)(ws + WS8_PMAX);
    float* psum = (float*)(ws + WS8_PSUM);
    float* ppv  = (float*)(ws + WS8_PPV);

    m_cumsum_kernel<<<4160, 256, 0, stream>>>(Q, K, V, M, out);
    topk_reg_kernel<<<B_ * H_, 64, 0, stream>>>(M, mt);
    attn_chunk_kernel<256, 8, false><<<B_ * H_ * 8, 256, 0, stream>>>(
        Q, K, V, mt, pmax, psum, ppv);
    attn_fin_kernel<8><<<B_ * H_ * NTOP, 64, 0, stream>>>(pmax, psum, ppv, mt, out);
  } else if (ws_size >= (size_t)WS_SMALL) {
    char* ws = (char*)d_ws;
    float* M  = (float*)(ws + WS_M_OFF);
    int*   mt = (int*)(ws + WS_MTOP_OFF);

    m_kernel<<<4096, 256, 0, stream>>>(Q, K, M);
    topk_kernel<<<B_ * H_, 256, 0, stream>>>(M, mt);
    cumsum_kernel<<<B_ * H_ * 2, 1024, 0, stream>>>(V, out);
    attn_kernel<<<B_ * H_ * NTOP, 256, 0, stream>>>(Q, K, V, mt, out);
  } else {
    cumsum_kernel<<<B_ * H_ * 2, 1024, 0, stream>>>(V, out);
    fused_kernel<<<B_ * H_, 256, 0, stream>>>(Q, K, V, out);
  }
}

// Round 4
// 206.577 us; speedup vs baseline: 1.4033x; 1.2955x over previous
//
#include <hip/hip_runtime.h>
#include <hip/hip_bf16.h>
#include <math.h>

// Problem constants (B,L,H,D fixed by setup_inputs; S == L)
#define B_   4
#define L_   2048
#define H_   8
#define D_   64
#define NTOP 38          // int(5*ln(2048)) = 38
#define SAMPK 38

// Verified RNG (r10 PASS): JAX partitionable threefry WITH randint key-split:
//   k2 = threefry((0,42), (0,1));  idx[t] = (y0^y1 @ (k2,(0,t))) & 2047.

// ---- d_ws layouts ----
#define WS_M_OFF    0                        // float  M[65536]     = 262144 B
#define WS_MTOP_OFF 262144                   // int    mtop[32*38]  =   4864 B
#define WS_SMALL    (WS_MTOP_OFF + 4864)     // 267008 B
// 8-chunk layout (2.84 MB, r1-verified fit):
#define NSLOT8      (B_ * H_ * NTOP * 8)     // 9728
#define WS8_PMAX    WS_SMALL
#define WS8_PSUM    (WS8_PMAX + NSLOT8 * 4)
#define WS8_PPV     (WS8_PSUM + NSLOT8 * 4)
#define WS8_TOTAL   (WS8_PPV + NSLOT8 * D_ * 4)          // 2835200
// 16-chunk layout (5.4 MB, r3-verified fit):
#define NSLOT16     (B_ * H_ * NTOP * 16)    // 19456
#define WS16_PMAX   WS_SMALL
#define WS16_PSUM   (WS16_PMAX + NSLOT16 * 4)
#define WS16_PPV    (WS16_PSUM + NSLOT16 * 4)
#define WS16_TOTAL  (WS16_PPV + NSLOT16 * D_ * 4)        // 5403392

#define CHUNK16 128                          // rows per chunk in the 16-chunk path
#define SPITCH  132                          // score-row pitch (128 + 4 pad)

// ---------------- Threefry-2x32 (standard 20-round, KAT-verified) ----------------
__device__ __forceinline__ uint32_t rotl32(uint32_t v, int d) {
  return (v << d) | (v >> (32 - d));
}

__device__ __forceinline__ void threefry2x32(uint32_t k0, uint32_t k1,
                                             uint32_t x0, uint32_t x1,
                                             uint32_t& y0, uint32_t& y1) {
  const uint32_t ks2 = k0 ^ k1 ^ 0x1BD11BDAu;
  const uint32_t ks[3] = {k0, k1, ks2};
  x0 += k0; x1 += k1;
  const int ra[4] = {13, 15, 26, 6};
  const int rb[4] = {17, 29, 16, 24};
#pragma unroll
  for (int g = 0; g < 5; ++g) {
    const int* r = (g & 1) ? rb : ra;
#pragma unroll
    for (int i = 0; i < 4; ++i) {
      x0 += x1;
      x1 = rotl32(x1, r[i]);
      x1 ^= x0;
    }
    x0 += ks[(g + 1) % 3];
    x1 += ks[(g + 2) % 3] + (uint32_t)(g + 1);
  }
  y0 = x0; y1 = x1;
}

__device__ __forceinline__ int sample_idx(int t) {
  uint32_t k2_0, k2_1, y0, y1;
  threefry2x32(0u, 42u, 0u, 1u, k2_0, k2_1);          // k2 = split(key(42))[1]
  threefry2x32(k2_0, k2_1, 0u, (uint32_t)t, y0, y1);  // partitionable draw
  return (int)((y0 ^ y1) & 2047u);
}

// ---------------- k1: fused m + cumsum (cumsum blocks stream in m's shadow) ----
// m j-loop 4-way unrolled (same fmax/add ORDER -> bitwise-identical M -> same topk).
__global__ __launch_bounds__(256) void m_cumsum_kernel(const float* __restrict__ Q,
                                                       const float* __restrict__ K,
                                                       const float* __restrict__ V,
                                                       float* __restrict__ M,
                                                       float* __restrict__ out) {
  __shared__ uint16_t sidx[16][SAMPK];   // m path
  __shared__ float cs[8][32];            // cumsum path

  int tid = threadIdx.x;

  if (blockIdx.x < 64) {
    int bI = blockIdx.x;
    int bh = bI >> 1, dhalf = bI & 1;
    int h = bh & (H_ - 1), b = bh >> 3;
    int dl = tid & 31, c = tid >> 5;       // 8 chunks of 256 rows
    const int CH = L_ / 8;                 // 256
    int d = dhalf * 32 + dl;
    size_t base = ((size_t)b * L_ * H_ + h) * D_ + d;
    const size_t ls = (size_t)H_ * D_;     // 512
    float s = 0.f;
    for (int l = c * CH; l < (c + 1) * CH; ++l)
      s += V[base + (size_t)l * ls];
    cs[c][dl] = s;
    __syncthreads();
    float run = 0.f;
    for (int cc = 0; cc < c; ++cc) run += cs[cc][dl];
    for (int l = c * CH; l < (c + 1) * CH; ++l) {
      run += V[base + (size_t)l * ls];
      out[base + (size_t)l * ls] = run;
    }
    return;
  }

  // ---- m path ----
  int bI = blockIdx.x - 64;             // 0..4095
  int j8 = bI >> 3;                     // 0..511
  int bh = (bI & 7) + 8 * (j8 >> 7);    // blockIdx%8 == bh%8 -> same XCD
  int chunk = j8 & 127;                 // 128 chunks of 16 q per bh
  int grp = tid >> 4, c = tid & 15;     // 16 groups x 16 lanes
  int q = chunk * 16 + grp;
  int h = bh & (H_ - 1), b = bh >> 3;

  for (int s = tid; s < 16 * SAMPK; s += 256) {
    int ql = s / SAMPK, jj = s - ql * SAMPK;
    sidx[ql][jj] = (uint16_t)sample_idx((chunk * 16 + ql) * SAMPK + jj);
  }
  __syncthreads();

  float4 qv = *(const float4*)(Q + (((size_t)b * L_ + q) * H_ + h) * D_ + 4 * c);
  const float* Kbase = K + ((size_t)b * L_ * H_ + h) * D_ + 4 * c;

  float mx = -1e30f, smv = 0.f;
  int j = 0;
  for (; j + 4 <= SAMPK; j += 4) {      // 4-deep MLP on the K gathers
    int r0 = (int)sidx[grp][j];
    int r1 = (int)sidx[grp][j + 1];
    int r2 = (int)sidx[grp][j + 2];
    int r3 = (int)sidx[grp][j + 3];
    float4 k0 = *(const float4*)(Kbase + (size_t)r0 * (H_ * D_));
    float4 k1 = *(const float4*)(Kbase + (size_t)r1 * (H_ * D_));
    float4 k2 = *(const float4*)(Kbase + (size_t)r2 * (H_ * D_));
    float4 k3 = *(const float4*)(Kbase + (size_t)r3 * (H_ * D_));
    float p0 = qv.x * k0.x + qv.y * k0.y + qv.z * k0.z + qv.w * k0.w;
    float p1 = qv.x * k1.x + qv.y * k1.y + qv.z * k1.z + qv.w * k1.w;
    float p2 = qv.x * k2.x + qv.y * k2.y + qv.z * k2.z + qv.w * k2.w;
    float p3 = qv.x * k3.x + qv.y * k3.y + qv.z * k3.z + qv.w * k3.w;
#pragma unroll
    for (int off = 1; off < 16; off <<= 1) {
      p0 += __shfl_xor(p0, off);
      p1 += __shfl_xor(p1, off);
      p2 += __shfl_xor(p2, off);
      p3 += __shfl_xor(p3, off);
    }
    mx = fmaxf(mx, p0); smv += p0;
    mx = fmaxf(mx, p1); smv += p1;
    mx = fmaxf(mx, p2); smv += p2;
    mx = fmaxf(mx, p3); smv += p3;
  }
  for (; j < SAMPK; ++j) {
    int r0 = (int)sidx[grp][j];
    float4 k0 = *(const float4*)(Kbase + (size_t)r0 * (H_ * D_));
    float p0 = qv.x * k0.x + qv.y * k0.y + qv.z * k0.z + qv.w * k0.w;
#pragma unroll
    for (int off = 1; off < 16; off <<= 1)
      p0 += __shfl_xor(p0, off);
    mx = fmaxf(mx, p0); smv += p0;
  }
  if (c == 0)
    M[(size_t)bh * L_ + q] = mx - smv * (1.0f / (float)L_);
}

// ---------------- k2: top-38, ONE WAVE, candidates fully in REGISTERS ----------------
__global__ __launch_bounds__(64) void topk_reg_kernel(const float* __restrict__ M,
                                                      int* __restrict__ mtop) {
  int bh = blockIdx.x;
  int lane = threadIdx.x;
  const float* Mrow = M + (size_t)bh * L_;

  float vals[32];
#pragma unroll
  for (int i = 0; i < 32; ++i)
    vals[i] = Mrow[lane + 64 * i];     // coalesced 256B/instr

  for (int u = 0; u < NTOP; ++u) {
    float bv = vals[0]; int bslot = 0;
#pragma unroll
    for (int i = 1; i < 32; ++i)
      if (vals[i] > bv) { bv = vals[i]; bslot = i; }
    float v = bv;
    int idx = lane + 64 * bslot;
#pragma unroll
    for (int off = 1; off < 64; off <<= 1) {
      float v2 = __shfl_xor(v, off);
      int   i2 = __shfl_xor(idx, off);
      if (v2 > v || (v2 == v && i2 < idx)) { v = v2; idx = i2; }
    }
    if (lane == 0) mtop[bh * NTOP + u] = idx;
    if ((idx & 63) == lane) {
      int slot = idx >> 6;
#pragma unroll
      for (int i = 0; i < 32; ++i)
        if (i == slot) vals[i] = -1e38f;
    }
  }
}

// ---------------- k4a: phase-split attention partials ----------------
// r3 lessons: shuffle-dots + replicated expf + 10% occupancy + bank conflicts.
// New structure, block = (bh, chunk of 128 rows), 512 threads, 2 barriers:
//  P1: stage K chunk (XOR-swizzled float4 slots), Q top-38, pos[38].
//  P2: scores GEMM-style: thread = (k-row, u-group); K row in 64 VGPRs; per u:
//      16 broadcast Q reads + 64 straight FMAs (no shuffles). S -> LDS.
//  P3: wave per u (stride 8): contiguous S reads, 6-shfl max/sum butterflies,
//      P written back (wave-coherent), PV with 4 V-rows in flight from L2,
//      per-chunk (max,sum,pv) partials -> workspace (NCHT=16, fin combines).
__global__ __launch_bounds__(512) void attn_split_kernel(const float* __restrict__ Q,
                                                         const float* __restrict__ K,
                                                         const float* __restrict__ V,
                                                         const int* __restrict__ mtop,
                                                         float* __restrict__ pmax,
                                                         float* __restrict__ psum,
                                                         float* __restrict__ ppv) {
  __shared__ float4 sK[CHUNK16 * 16];      // 32 KB, slot-swizzled
  __shared__ float  sS[NTOP * SPITCH];     // 19.6 KB scores/probs
  __shared__ float4 sQ[NTOP * 16];         // 9.5 KB
  __shared__ int    spos[NTOP];

  int bI = blockIdx.x;
  int c = bI & 15;                // chunk
  int bh = bI >> 4;
  int h = bh & (H_ - 1), b = bh >> 3;
  int kstart = c * CHUNK16;
  int tid = threadIdx.x;

  // block-uniform early exit (before any barrier / LDS write)
  int maxpos = -1;
  for (int u = 0; u < NTOP; ++u) {
    int p = mtop[bh * NTOP + u];
    maxpos = max(maxpos, p);
  }
  if (maxpos < kstart) return;

  const float* Kb = K + ((size_t)b * L_ * H_ + h) * D_;
  const float* Vb = V + ((size_t)b * L_ * H_ + h) * D_;
  const float* Qb = Q + ((size_t)b * L_ * H_ + h) * D_;

  // ---- P1: stage ----
  if (tid < NTOP) {
    int p = mtop[bh * NTOP + tid];
    if (p < 0) p = 0;
    if (p > L_ - 1) p = L_ - 1;
    spos[tid] = p;
  }
  for (int s = tid; s < CHUNK16 * 16; s += 512) {
    int row = s >> 4, f = s & 15;
    sK[row * 16 + (f ^ (row & 15))] =
        *(const float4*)(Kb + (size_t)(kstart + row) * (H_ * D_) + 4 * f);
  }
  for (int s = tid; s < NTOP * 16; s += 512) {
    int u = s >> 4, f = s & 15;
    int p = mtop[bh * NTOP + u];
    if (p < 0) p = 0;
    if (p > L_ - 1) p = L_ - 1;
    sQ[s] = *(const float4*)(Qb + (size_t)p * (H_ * D_) + 4 * f);
  }
  __syncthreads();                // barrier 1

  // ---- P2: scores ----
  {
    int k = tid & 127;            // row within chunk (wave spans 64 consecutive k)
    int ug = tid >> 7;            // 0..3, wave-uniform
    float4 kreg[16];
#pragma unroll
    for (int f = 0; f < 16; ++f)
      kreg[f] = sK[k * 16 + (f ^ (k & 15))];

    int u0 = ug * 10, u1 = min(NTOP, u0 + 10);
    for (int u = u0; u < u1; ++u) {
      int pos = spos[u];
      if (pos < kstart) continue;         // block/wave-uniform per u
      int kloc = pos - kstart;            // >= 0
      float dot = 0.f;
#pragma unroll
      for (int f = 0; f < 16; ++f) {
        float4 qf = sQ[u * 16 + f];       // broadcast read
        dot += kreg[f].x * qf.x + kreg[f].y * qf.y
             + kreg[f].z * qf.z + kreg[f].w * qf.w;
      }
      sS[u * SPITCH + k] = (k <= kloc) ? dot * 0.125f : -1e30f;
    }
  }
  __syncthreads();                // barrier 2

  // ---- P3: softmax + PV per wave (no more barriers) ----
  int w = tid >> 6, lane = tid & 63;
  int kq = lane >> 4, dq = lane & 15;
  for (int u = w; u < NTOP; u += 8) {
    int pos = spos[u];
    if (pos < kstart) continue;
    int kcnt = min(CHUNK16, pos + 1 - kstart);

    float s0 = sS[u * SPITCH + lane];
    float s1 = sS[u * SPITCH + 64 + lane];
    float m = fmaxf(s0, s1);
#pragma unroll
    for (int off = 1; off < 64; off <<= 1)
      m = fmaxf(m, __shfl_xor(m, off));
    float p0 = expf(s0 - m), p1 = expf(s1 - m);
    sS[u * SPITCH + lane] = p0;           // wave-coherent write-back
    sS[u * SPITCH + 64 + lane] = p1;
    float sum = p0 + p1;
#pragma unroll
    for (int off = 1; off < 64; off <<= 1)
      sum += __shfl_xor(sum, off);

    // PV: 4 rows in flight; lane = (kq,dq); V from L2, 256B coalesced per row
    float4 acc = make_float4(0.f, 0.f, 0.f, 0.f);
    for (int k0 = 0; k0 < kcnt; k0 += 4) {
      int kk = k0 + kq;
      if (kk < kcnt) {
        float p = sS[u * SPITCH + kk];    // 4 distinct addrs -> bcast, no conflict
        float4 v4 = *(const float4*)(Vb + (size_t)(kstart + kk) * (H_ * D_) + 4 * dq);
        acc.x += p * v4.x; acc.y += p * v4.y;
        acc.z += p * v4.z; acc.w += p * v4.w;
      }
    }
    acc.x += __shfl_xor(acc.x, 16); acc.y += __shfl_xor(acc.y, 16);
    acc.z += __shfl_xor(acc.z, 16); acc.w += __shfl_xor(acc.w, 16);
    acc.x += __shfl_xor(acc.x, 32); acc.y += __shfl_xor(acc.y, 32);
    acc.z += __shfl_xor(acc.z, 32); acc.w += __shfl_xor(acc.w, 32);

    int slot = (bh * NTOP + u) * 16 + c;
    if (lane < 16)
      *(float4*)(ppv + (size_t)slot * D_ + 4 * lane) = acc;
    if (lane == 0) { pmax[slot] = m; psum[slot] = sum; }
  }
}

// ---------------- k4b: combine chunk partials, write out row ----------------
template <int NCHT>
__global__ __launch_bounds__(64) void attn_fin_kernel(const float* __restrict__ pmax,
                                                      const float* __restrict__ psum,
                                                      const float* __restrict__ ppv,
                                                      const int* __restrict__ mtop,
                                                      float* __restrict__ out) {
  const int CH = L_ / NCHT;
  int uu = blockIdx.x;            // 0..1215 == bh*NTOP + u
  int bh = uu / NTOP;
  int h = bh & (H_ - 1), b = bh >> 3;
  int pos = mtop[uu];
  if (pos < 0) pos = 0;
  if (pos > L_ - 1) pos = L_ - 1;
  int klen = pos + 1;
  int nch = (klen + CH - 1) / CH;
  int tid = threadIdx.x;          // == d

  int base = uu * NCHT;
  float gmax = -1e30f;
#pragma unroll
  for (int cc = 0; cc < NCHT; ++cc)
    if (cc < nch) gmax = fmaxf(gmax, pmax[base + cc]);

  float gsum = 0.f, acc = 0.f;
#pragma unroll
  for (int cc = 0; cc < NCHT; ++cc) {
    if (cc < nch) {
      float w0 = expf(pmax[base + cc] - gmax);
      gsum += psum[base + cc] * w0;
      acc += ppv[(size_t)(base + cc) * D_ + tid] * w0;
    }
  }
  out[(((size_t)b * L_ + pos) * H_ + h) * D_ + tid] = acc / gsum;
}

// ---------------- WS8 fallback: r1's split-K partials (74us, verified) ----------------
__global__ __launch_bounds__(256) void attn_part_kernel(const float* __restrict__ Q,
                                                        const float* __restrict__ K,
                                                        const float* __restrict__ V,
                                                        const int* __restrict__ mtop,
                                                        float* __restrict__ pmax,
                                                        float* __restrict__ psum,
                                                        float* __restrict__ ppv) {
  const int CHUNK = 256, NCH = 8;
  int bI = blockIdx.x;
  int c = bI & 7;
  int uu = bI >> 3;
  int bh = uu / NTOP;
  int h = bh & (H_ - 1), b = bh >> 3;

  int pos = mtop[uu];
  if (pos < 0) pos = 0;
  if (pos > L_ - 1) pos = L_ - 1;
  int klen = pos + 1;
  int kstart = c * CHUNK;
  if (kstart >= klen) return;
  int kcnt = min(CHUNK, klen - kstart);

  int tid = threadIdx.x;
  int c16 = tid & 15, g = tid >> 4;

  __shared__ float sc[CHUNK];
  __shared__ float red[256];
  __shared__ float4 part4[16][16];

  float4 qreg = *(const float4*)(Q + (((size_t)b * L_ + pos) * H_ + h) * D_ + 4 * c16);
  const float* Kbase = K + ((size_t)b * L_ * H_ + h) * D_ + 4 * c16;
  float lmax = -1e30f;
  for (int k = g; k < kcnt; k += 16) {
    float4 kv = *(const float4*)(Kbase + (size_t)(kstart + k) * (H_ * D_));
    float part = qreg.x * kv.x + qreg.y * kv.y + qreg.z * kv.z + qreg.w * kv.w;
#pragma unroll
    for (int off = 1; off < 16; off <<= 1)
      part += __shfl_xor(part, off);
    part *= 0.125f;
    if (c16 == 0) sc[k] = part;
    lmax = fmaxf(lmax, part);
  }
  red[tid] = lmax;
  __syncthreads();
  for (int s = 128; s > 0; s >>= 1) {
    if (tid < s) red[tid] = fmaxf(red[tid], red[tid + s]);
    __syncthreads();
  }
  float mx = red[0];
  __syncthreads();

  float lsum = 0.f;
  for (int k = tid; k < kcnt; k += 256) {
    float p = expf(sc[k] - mx);
    sc[k] = p;
    lsum += p;
  }
  red[tid] = lsum;
  __syncthreads();
  for (int s = 128; s > 0; s >>= 1) {
    if (tid < s) red[tid] += red[tid + s];
    __syncthreads();
  }
  float csum = red[0];
  __syncthreads();

  float4 acc = make_float4(0.f, 0.f, 0.f, 0.f);
  const float* Vbase = V + ((size_t)b * L_ * H_ + h) * D_ + 4 * c16;
  for (int k = g; k < kcnt; k += 16) {
    float p = sc[k];
    float4 v4 = *(const float4*)(Vbase + (size_t)(kstart + k) * (H_ * D_));
    acc.x += p * v4.x; acc.y += p * v4.y; acc.z += p * v4.z; acc.w += p * v4.w;
  }
  part4[g][c16] = acc;
  __syncthreads();
#pragma unroll
  for (int s = 8; s > 0; s >>= 1) {
    if (g < s) {
      float4 o = part4[g + s][c16];
      float4 m = part4[g][c16];
      m.x += o.x; m.y += o.y; m.z += o.z; m.w += o.w;
      part4[g][c16] = m;
    }
    __syncthreads();
  }

  int slot = uu * NCH + c;
  if (tid == 0) { pmax[slot] = mx; psum[slot] = csum; }
  if (tid < 16)
    *(float4*)(ppv + (size_t)slot * D_ + 4 * tid) = part4[0][tid];
}

// ================= fallback kernels (small-ws / zero-ws paths) =================
__global__ __launch_bounds__(256) void m_kernel(const float* __restrict__ Q,
                                                const float* __restrict__ K,
                                                float* __restrict__ M) {
  int bI = blockIdx.x;
  int j8 = bI >> 3;
  int bh = (bI & 7) + 8 * (j8 >> 7);
  int chunk = j8 & 127;
  int tid = threadIdx.x;
  int grp = tid >> 4, c = tid & 15;
  int q = chunk * 16 + grp;
  int h = bh & (H_ - 1), b = bh >> 3;

  __shared__ uint16_t sidx[16][SAMPK];
  for (int s = tid; s < 16 * SAMPK; s += 256) {
    int ql = s / SAMPK, jj = s - ql * SAMPK;
    sidx[ql][jj] = (uint16_t)sample_idx((chunk * 16 + ql) * SAMPK + jj);
  }
  __syncthreads();

  float4 qv = *(const float4*)(Q + (((size_t)b * L_ + q) * H_ + h) * D_ + 4 * c);
  const float* Kbase = K + ((size_t)b * L_ * H_ + h) * D_ + 4 * c;

  float mx = -1e30f, smv = 0.f;
  for (int j = 0; j < SAMPK; ++j) {
    int row = (int)sidx[grp][j];
    float4 kv = *(const float4*)(Kbase + (size_t)row * (H_ * D_));
    float part = qv.x * kv.x + qv.y * kv.y + qv.z * kv.z + qv.w * kv.w;
#pragma unroll
    for (int off = 1; off < 16; off <<= 1)
      part += __shfl_xor(part, off);
    mx = fmaxf(mx, part);
    smv += part;
  }
  if (c == 0)
    M[(size_t)bh * L_ + q] = mx - smv * (1.0f / (float)L_);
}

__global__ __launch_bounds__(1024) void cumsum_kernel(const float* __restrict__ V,
                                                      float* __restrict__ out) {
  int bI = blockIdx.x;
  int bh = bI >> 1, dhalf = bI & 1;
  int h = bh & (H_ - 1), b = bh >> 3;
  int tid = threadIdx.x;
  int dl = tid & 31, c = tid >> 5;
  int d = dhalf * 32 + dl;
  const int CH = L_ / 32;
  __shared__ float cs[32][32];
  size_t base = ((size_t)b * L_ * H_ + h) * D_ + d;
  const size_t ls = (size_t)H_ * D_;
  float s = 0.f;
  for (int l = c * CH; l < (c + 1) * CH; ++l)
    s += V[base + (size_t)l * ls];
  cs[c][dl] = s;
  __syncthreads();
  float run = 0.f;
  for (int cc = 0; cc < c; ++cc) run += cs[cc][dl];
  for (int l = c * CH; l < (c + 1) * CH; ++l) {
    run += V[base + (size_t)l * ls];
    out[base + (size_t)l * ls] = run;
  }
}

__global__ __launch_bounds__(256) void topk_kernel(const float* __restrict__ M,
                                                   int* __restrict__ mtop) {
  int bh = blockIdx.x;
  int tid = threadIdx.x;
  __shared__ float sm[L_];
  __shared__ float wv[4];
  __shared__ int   wi[4];
  __shared__ int   ssel;
  const float* Mrow = M + (size_t)bh * L_;
  for (int i = tid; i < L_; i += 256) sm[i] = Mrow[i];
  __syncthreads();

  float bv = -1e38f; int bi = -1;
  for (int i = tid; i < L_; i += 256) {
    float v = sm[i];
    if (v > bv) { bv = v; bi = i; }
  }

  int lane = tid & 63, wid = tid >> 6;
  for (int u = 0; u < NTOP; ++u) {
    float v = bv; int i = bi;
#pragma unroll
    for (int off = 32; off > 0; off >>= 1) {
      float v2 = __shfl_down(v, off);
      int   i2 = __shfl_down(i, off);
      if (v2 > v || (v2 == v && i2 >= 0 && (i < 0 || i2 < i))) { v = v2; i = i2; }
    }
    if (lane == 0) { wv[wid] = v; wi[wid] = i; }
    __syncthreads();
    if (tid == 0) {
      float fv = wv[0]; int fi = wi[0];
#pragma unroll
      for (int w = 1; w < 4; ++w) {
        if (wv[w] > fv || (wv[w] == fv && wi[w] >= 0 && (fi < 0 || wi[w] < fi))) {
          fv = wv[w]; fi = wi[w];
        }
      }
      if (fi < 0) fi = 0;
      mtop[bh * NTOP + u] = fi;
      sm[fi] = -1e38f;
      ssel = fi;
    }
    __syncthreads();
    int sel = ssel;
    if (bi == sel) {
      bv = -1e38f; bi = -1;
      for (int i2 = tid; i2 < L_; i2 += 256) {
        float vv = sm[i2];
        if (vv > bv) { bv = vv; bi = i2; }
      }
    }
  }
}

__global__ __launch_bounds__(256) void attn_kernel(const float* __restrict__ Q,
                                                   const float* __restrict__ K,
                                                   const float* __restrict__ V,
                                                   const int* __restrict__ mtop,
                                                   float* __restrict__ out) {
  int bI = blockIdx.x;
  int j = bI >> 3;
  int u = j % NTOP;
  int bh = (bI & 7) + 8 * (j / NTOP);
  int h = bh & (H_ - 1), b = bh >> 3;
  int tid = threadIdx.x;

  int pos = mtop[bh * NTOP + u];
  if (pos < 0) pos = 0;
  if (pos > L_ - 1) pos = L_ - 1;
  int klen = pos + 1;

  __shared__ float qs[D_];
  __shared__ float sc[L_];
  __shared__ float redv[256];
  __shared__ float4 part4[16][16];

  if (tid < D_)
    qs[tid] = Q[(((size_t)b * L_ + pos) * H_ + h) * D_ + tid];
  __syncthreads();

  int c16 = tid & 15, g = tid >> 4;
  float4 qreg = *(const float4*)(qs + 4 * c16);
  const float* Kbase = K + ((size_t)b * L_ * H_ + h) * D_ + 4 * c16;
  float lmax = -1e30f;
  for (int k = g; k < klen; k += 16) {
    float4 kv = *(const float4*)(Kbase + (size_t)k * (H_ * D_));
    float part = qreg.x * kv.x + qreg.y * kv.y + qreg.z * kv.z + qreg.w * kv.w;
#pragma unroll
    for (int off = 1; off < 16; off <<= 1)
      part += __shfl_xor(part, off);
    part *= 0.125f;
    if (c16 == 0) sc[k] = part;
    lmax = fmaxf(lmax, part);
  }
  redv[tid] = lmax;
  __syncthreads();
  for (int s = 128; s > 0; s >>= 1) {
    if (tid < s) redv[tid] = fmaxf(redv[tid], redv[tid + s]);
    __syncthreads();
  }
  float mx = redv[0];
  __syncthreads();

  float lsum = 0.f;
  for (int k = tid; k < klen; k += 256) {
    float p = expf(sc[k] - mx);
    sc[k] = p;
    lsum += p;
  }
  redv[tid] = lsum;
  __syncthreads();
  for (int s = 128; s > 0; s >>= 1) {
    if (tid < s) redv[tid] += redv[tid + s];
    __syncthreads();
  }
  float inv = 1.0f / redv[0];
  __syncthreads();

  float4 acc = make_float4(0.f, 0.f, 0.f, 0.f);
  const float* Vbase = V + ((size_t)b * L_ * H_ + h) * D_ + 4 * c16;
  for (int k = g; k < klen; k += 16) {
    float p = sc[k];
    float4 v4 = *(const float4*)(Vbase + (size_t)k * (H_ * D_));
    acc.x += p * v4.x; acc.y += p * v4.y; acc.z += p * v4.z; acc.w += p * v4.w;
  }
  part4[g][c16] = acc;
  __syncthreads();
#pragma unroll
  for (int s = 8; s > 0; s >>= 1) {
    if (g < s) {
      float4 o = part4[g + s][c16];
      float4 m = part4[g][c16];
      m.x += o.x; m.y += o.y; m.z += o.z; m.w += o.w;
      part4[g][c16] = m;
    }
    __syncthreads();
  }
  if (tid < 16) {
    float4 r = part4[0][tid];
    r.x *= inv; r.y *= inv; r.z *= inv; r.w *= inv;
    *(float4*)(out + (((size_t)b * L_ + pos) * H_ + h) * D_ + 4 * tid) = r;
  }
}

__global__ __launch_bounds__(256) void fused_kernel(const float* __restrict__ Q,
                                                    const float* __restrict__ K,
                                                    const float* __restrict__ V,
                                                    float* __restrict__ out) {
  int bh = blockIdx.x;
  int h = bh % H_, b = bh / H_;
  int tid = threadIdx.x;

  __shared__ float sm[L_];
  __shared__ float redv[256];
  __shared__ int   redi[256];
  __shared__ int   mtop_s[NTOP];
  __shared__ float qs[D_];
  __shared__ float part[4][D_];

  for (int q = tid; q < L_; q += 256) {
    const float4* q4 = (const float4*)(Q + (((size_t)b * L_ + q) * H_ + h) * D_);
    float4 qv[16];
#pragma unroll
    for (int i = 0; i < 16; ++i) qv[i] = q4[i];
    float mx = -1e30f, smv = 0.f;
    for (int j = 0; j < SAMPK; ++j) {
      int kk = sample_idx(q * SAMPK + j);
      const float4* k4 = (const float4*)(K + (((size_t)b * L_ + kk) * H_ + h) * D_);
      float dot = 0.f;
#pragma unroll
      for (int i = 0; i < 16; ++i) {
        float4 kv = k4[i];
        dot += qv[i].x * kv.x + qv[i].y * kv.y + qv[i].z * kv.z + qv[i].w * kv.w;
      }
      mx = fmaxf(mx, dot);
      smv += dot;
    }
    sm[q] = mx - smv * (1.0f / (float)L_);
  }
  __syncthreads();

  for (int u = 0; u < NTOP; ++u) {
    float bv = -1e38f; int bi = -1;
    for (int i = tid; i < L_; i += 256) {
      float v = sm[i];
      if (v > bv) { bv = v; bi = i; }
    }
    redv[tid] = bv; redi[tid] = bi;
    __syncthreads();
    for (int s = 128; s > 0; s >>= 1) {
      if (tid < s) {
        float v2 = redv[tid + s]; int i2 = redi[tid + s];
        if (v2 > redv[tid] ||
            (v2 == redv[tid] && i2 >= 0 && (redi[tid] < 0 || i2 < redi[tid]))) {
          redv[tid] = v2; redi[tid] = i2;
        }
      }
      __syncthreads();
    }
    if (tid == 0) {
      int sel = redi[0];
      if (sel < 0) sel = 0;
      mtop_s[u] = sel;
      sm[sel] = -1e38f;
    }
    __syncthreads();
  }

  for (int u = 0; u < NTOP; ++u) {
    int pos = mtop_s[u];
    if (pos < 0) pos = 0;
    if (pos > L_ - 1) pos = L_ - 1;
    int klen = pos + 1;

    __syncthreads();
    if (tid < D_)
      qs[tid] = Q[(((size_t)b * L_ + pos) * H_ + h) * D_ + tid];
    __syncthreads();

    float lmax = -1e30f;
    for (int k = tid; k < klen; k += 256) {
      const float4* k4 = (const float4*)(K + (((size_t)b * L_ + k) * H_ + h) * D_);
      float dot = 0.f;
#pragma unroll
      for (int i = 0; i < 16; ++i) {
        float4 kv = k4[i];
        dot += qs[4 * i] * kv.x + qs[4 * i + 1] * kv.y
             + qs[4 * i + 2] * kv.z + qs[4 * i + 3] * kv.w;
      }
      dot *= 0.125f;
      sm[k] = dot;
      lmax = fmaxf(lmax, dot);
    }
    redv[tid] = lmax;
    __syncthreads();
    for (int s = 128; s > 0; s >>= 1) {
      if (tid < s) redv[tid] = fmaxf(redv[tid], redv[tid + s]);
      __syncthreads();
    }
    float mx = redv[0];
    __syncthreads();

    float lsum = 0.f;
    for (int k = tid; k < klen; k += 256) {
      float p = expf(sm[k] - mx);
      sm[k] = p;
      lsum += p;
    }
    redv[tid] = lsum;
    __syncthreads();
    for (int s = 128; s > 0; s >>= 1) {
      if (tid < s) redv[tid] += redv[tid + s];
      __syncthreads();
    }
    float inv = 1.0f / redv[0];
    __syncthreads();

    int d = tid & 63, slice = tid >> 6;
    float acc = 0.f;
    for (int k = slice; k < klen; k += 4)
      acc += sm[k] * V[(((size_t)b * L_ + k) * H_ + h) * D_ + d];
    part[slice][d] = acc;
    __syncthreads();
    if (tid < D_) {
      float r = (part[0][tid] + part[1][tid]) + (part[2][tid] + part[3][tid]);
      out[(((size_t)b * L_ + pos) * H_ + h) * D_ + tid] = r * inv;
    }
  }
}

extern "C" void kernel_launch(void* const* d_in, const int* in_sizes, int n_in,
                              void* d_out, int out_size, void* d_ws, size_t ws_size,
                              hipStream_t stream) {
  const float* Q = (const float*)d_in[0];
  const float* K = (const float*)d_in[1];
  const float* V = (const float*)d_in[2];
  float* out = (float*)d_out;

  if (ws_size >= (size_t)WS16_TOTAL) {
    char* ws = (char*)d_ws;
    float* M    = (float*)(ws + WS_M_OFF);
    int*   mt   = (int*)(ws + WS_MTOP_OFF);
    float* pmax = (float*)(ws + WS16_PMAX);
    float* psum = (float*)(ws + WS16_PSUM);
    float* ppv  = (float*)(ws + WS16_PPV);

    m_cumsum_kernel<<<4160, 256, 0, stream>>>(Q, K, V, M, out);
    topk_reg_kernel<<<B_ * H_, 64, 0, stream>>>(M, mt);
    attn_split_kernel<<<B_ * H_ * 16, 512, 0, stream>>>(Q, K, V, mt, pmax, psum, ppv);
    attn_fin_kernel<16><<<B_ * H_ * NTOP, 64, 0, stream>>>(pmax, psum, ppv, mt, out);
  } else if (ws_size >= (size_t)WS8_TOTAL) {
    char* ws = (char*)d_ws;
    float* M    = (float*)(ws + WS_M_OFF);
    int*   mt   = (int*)(ws + WS_MTOP_OFF);
    float* pmax = (float*)(ws + WS8_PMAX);
    float* psum = (float*)(ws + WS8_PSUM);
    float* ppv  = (float*)(ws + WS8_PPV);

    m_cumsum_kernel<<<4160, 256, 0, stream>>>(Q, K, V, M, out);
    topk_reg_kernel<<<B_ * H_, 64, 0, stream>>>(M, mt);
    attn_part_kernel<<<NSLOT8, 256, 0, stream>>>(Q, K, V, mt, pmax, psum, ppv);
    attn_fin_kernel<8><<<B_ * H_ * NTOP, 64, 0, stream>>>(pmax, psum, ppv, mt, out);
  } else if (ws_size >= (size_t)WS_SMALL) {
    char* ws = (char*)d_ws;
    float* M  = (float*)(ws + WS_M_OFF);
    int*   mt = (int*)(ws + WS_MTOP_OFF);

    m_kernel<<<4096, 256, 0, stream>>>(Q, K, M);
    topk_kernel<<<B_ * H_, 256, 0, stream>>>(M, mt);
    cumsum_kernel<<<B_ * H_ * 2, 1024, 0, stream>>>(V, out);
    attn_kernel<<<B_ * H_ * NTOP, 256, 0, stream>>>(Q, K, V, mt, out);
  } else {
    cumsum_kernel<<<B_ * H_ * 2, 1024, 0, stream>>>(V, out);
    fused_kernel<<<B_ * H_, 256, 0, stream>>>(Q, K, V, out);
  }
}